// Round 20
// baseline (98.401 us; speedup 1.0000x reference)
//
#include <hip/hip_runtime.h>

typedef unsigned short u16;
typedef __attribute__((ext_vector_type(8))) short bf16x8;
typedef __attribute__((ext_vector_type(8))) unsigned short u16x8;
typedef __attribute__((ext_vector_type(4))) float f32x4;
typedef __attribute__((ext_vector_type(16))) float f32x16;
typedef __attribute__((ext_vector_type(4))) unsigned int u32x4;

#define MFMA16(a, b, c) __builtin_amdgcn_mfma_f32_16x16x32_bf16((a), (b), (c), 0, 0, 0)
#define MFMA32(a, b, c) __builtin_amdgcn_mfma_f32_32x32x16_bf16((a), (b), (c), 0, 0, 0)

static constexpr int CB = 4, CT = 2048, CH = 512, CN = 8, CD = 64;
static constexpr int CM = CB * CT;  // 8192 rows

__device__ __forceinline__ u16 f2bf(float f) {
    union { float f; unsigned int i; } v; v.f = f;
    unsigned int r = v.i + 0x7FFFu + ((v.i >> 16) & 1u);
    return (u16)(r >> 16);
}

// kept-count: # of unmasked cols s in [0, t]  (masked: s>=4 && s%3==1)
__device__ __forceinline__ int kc_of(int t) {
    return t + 1 - ((t >= 4) ? ((t - 1) / 3) : 0);
}

// async global->LDS, 16B per lane (wave-uniform LDS base + lane*16)
__device__ __forceinline__ void gl16(const u16* g, u16* l) {
    __builtin_amdgcn_global_load_lds(
        (const __attribute__((address_space(1))) void*)g,
        (__attribute__((address_space(3))) void*)l, 16, 0, 0);
}

// ---------------- fused prep kernel (R15-verified, R17-isolated -3.3us) ----------------
// blocks [0,1024): Wt transpose+cvt; [1024,3072): rope table; [3072,5120): x->bf16.
__global__ __launch_bounds__(256) void prep_kernel(
    const float* __restrict__ x, u16* __restrict__ xb,
    const float* __restrict__ Wq, const float* __restrict__ Wk,
    const float* __restrict__ Wv, const float* __restrict__ Wo,
    u16* __restrict__ Wt, float2* __restrict__ tab) {
    const int blk = blockIdx.x;
    if (blk < 1024) {
        __shared__ float tile[32][33];
        const int z = blk >> 8, rem = blk & 255;
        const int n0 = (rem & 15) * 32, k0 = (rem >> 4) * 32;
        const float* W = (z == 0) ? Wq : (z == 1) ? Wk : (z == 2) ? Wv : Wo;
        u16* dst = Wt + (size_t)z * CH * CH;
        const int tx = threadIdx.x & 31, ty = threadIdx.x >> 5;  // 32 x 8
        for (int j = 0; j < 32; j += 8)
            tile[ty + j][tx] = W[(size_t)(k0 + ty + j) * CH + n0 + tx];
        __syncthreads();
        for (int j = 0; j < 32; j += 8)
            dst[(size_t)(n0 + ty + j) * CH + k0 + tx] = f2bf(tile[tx][ty + j]);
    } else if (blk < 3072) {
        const int i = (blk - 1024) * 256 + threadIdx.x;  // i < CT*256 exactly
        const int t = i >> 8, h = i & 255;
        float inv = exp2f(-(float)h * (13.287712379549449f / 256.0f));
        float s, c;
        sincosf((float)t * inv, &s, &c);
        tab[i] = make_float2(c, s);
    } else {
        const int n4 = CM * CH / 4;
        const float4* x4 = (const float4*)x;
        for (int i = (blk - 3072) * 256 + threadIdx.x; i < n4; i += 2048 * 256) {
            float4 v = x4[i];
            unsigned long long pack = (unsigned long long)f2bf(v.x)
                                    | ((unsigned long long)f2bf(v.y) << 16)
                                    | ((unsigned long long)f2bf(v.z) << 32)
                                    | ((unsigned long long)f2bf(v.w) << 48);
            ((unsigned long long*)xb)[i] = pack;
        }
    }
}

// ---------------- qkv GEMM (128x192 tile, BK=32, 12 waves x 64x32) ----------------
// R20: SAME per-wave geometry as proven R14 (64x32 wave, acc[4][2], 8 MFMA / 6 loads,
// ~96 VGPR) — only the block/grid decomposition changes: 12 waves/block, grid 64x8 =
// 512 blocks = exactly 2 FULL rounds at 1 block/CU (R14's 768 = 1.5 rounds, tail at
// half machine). Staging: waves 0-7 stage A rows w*16..+16; all 12 stage B rows w*16.

__device__ __forceinline__ void gemm_bt_qkv(const u16* __restrict__ A, const u16* __restrict__ Bt,
                                            int m0, int n0, f32x4 acc[4][2]) {
    __shared__ __align__(16) u16 Al[128 * 32];
    __shared__ __align__(16) u16 Bl[192 * 32];
    const int tid = threadIdx.x;
    const int lane = tid & 63;
    const int w = tid >> 6;              // 0..11
    const int wm = w / 6, wn = w % 6;    // 2M x 6N, wave = 64x32
    const int lg = lane >> 4, lr = lane & 15;

    // staging: lane l -> row base + (l>>2), chunk (l&3); src chunk = (l&3)^((l>>3)&3)
    // (valid for any 16-multiple row base).
    const int srow = lane >> 2;
    const int schunk = ((lane & 3) ^ ((lane >> 3) & 3)) * 8;
    const u16* ga = A  + (size_t)(m0 + w * 16 + srow) * CH + schunk;  // used by w<8
    const u16* gb = Bt + (size_t)(n0 + w * 16 + srow) * CH + schunk;

    // read swizzle term: chunk = lg ^ ((lr>>1)&3)
    const int rchunk = (lg ^ ((lr >> 1) & 3)) * 8;

    for (int k0 = 0; k0 < CH; k0 += 32) {
        __syncthreads();
        if (w < 8) gl16(ga + k0, Al + w * 512);
        gl16(gb + k0, Bl + w * 512);
        __syncthreads();
        bf16x8 af[4], bfr[2];
#pragma unroll
        for (int i = 0; i < 4; ++i)
            af[i] = *(const bf16x8*)(Al + (wm * 64 + i * 16 + lr) * 32 + rchunk);
#pragma unroll
        for (int i = 0; i < 2; ++i)
            bfr[i] = *(const bf16x8*)(Bl + (wn * 32 + i * 16 + lr) * 32 + rchunk);
#pragma unroll
        for (int mi = 0; mi < 4; ++mi)
#pragma unroll
            for (int ni = 0; ni < 2; ++ni)
                acc[mi][ni] = MFMA16(af[mi], bfr[ni], acc[mi][ni]);
    }
}

// QKV GEMM epilogue: +bias, RoPE(q,k), q *= 0.125*log2(e), COMPACTED frag-major k/v.
// seg = c>>9 per-ni (192-tiles straddle q/k/v boundaries; 16-col frags never do).
__global__ __launch_bounds__(768) void gemm_qkv_kernel(
    const u16* __restrict__ xb, const u16* __restrict__ Wt,
    const float* __restrict__ bq, const float* __restrict__ bk, const float* __restrict__ bv,
    const float2* __restrict__ tab,
    u16* __restrict__ q_ws, u16* __restrict__ k_ws, u16* __restrict__ v_t) {
    f32x4 acc[4][2];
#pragma unroll
    for (int mi = 0; mi < 4; ++mi)
#pragma unroll
        for (int ni = 0; ni < 2; ++ni)
#pragma unroll
            for (int e = 0; e < 4; ++e) acc[mi][ni][e] = 0.f;

    const int m0 = blockIdx.x * 128, n0 = blockIdx.y * 192;
    gemm_bt_qkv(xb, Wt, m0, n0, acc);

    const int lane = threadIdx.x & 63;
    const int w = threadIdx.x >> 6;
    const int wm = w / 6, wn = w % 6;
    const int lg = lane >> 4, lr = lane & 15;

#pragma unroll
    for (int ni = 0; ni < 2; ++ni) {
        const int c = n0 + wn * 32 + ni * 16 + lr;
        const int seg = c >> 9;  // wave-uniform per ni (16-col frag never straddles 512)
        const int cc = c & 511;
        const int nh = cc >> 6, d = cc & 63;
        const float* bias_p = (seg == 0) ? bq : (seg == 1) ? bk : bv;
        const float bias = bias_p[cc];
#pragma unroll
        for (int mi = 0; mi < 4; ++mi) {
#pragma unroll
            for (int r = 0; r < 4; ++r) {
                const int row = m0 + wm * 64 + mi * 16 + lg * 4 + r;
                const int b = row >> 11, t = row & 2047;
                float val = acc[mi][ni][r] + bias;
                if (seg < 2) {  // RoPE: pair (c, c^1) lives in lane^1
                    float2 cs = tab[t * 256 + (cc >> 1)];
                    float partner = __shfl_xor(val, 1);
                    val = val * cs.x + ((lane & 1) ? partner * cs.y : -partner * cs.y);
                }
                if (seg == 0) {
                    val *= 0.18033688011112f;  // (1/8)*log2(e): softmax via exp2
                    q_ws[(size_t)((b * CN + nh) * CT + t) * CD + d] = f2bf(val);
                } else {
                    const bool msk = (t >= 4) && (t % 3 == 1);
                    if (!msk) {
                        const int ci = t - ((t >= 4) ? ((t - 1) / 3) : 0);
                        const int tile = ci >> 5, sl = ci & 31;
                        const size_t tb = (size_t)(b * CN + nh) * CT * CD + (size_t)tile * 2048;
                        if (seg == 1) {
                            const int cF = d >> 4, hF = (d >> 3) & 1, jF = d & 7;
                            k_ws[tb + ((cF * 2 + hF) * 32 + sl) * 8 + jF] = f2bf(val);
                        } else {
                            const int kbF = sl >> 4, hF = (sl >> 3) & 1, jF = sl & 7;
                            const int dhF = d >> 5, qlF = d & 31;
                            v_t[tb + (((dhF * 2 + kbF) * 2 + hF) * 32 + qlF) * 8 + jF] = f2bf(val);
                        }
                    }
                }
            }
        }
    }
}

// ---------------- out GEMM (64x128 tile, BK=32, 8 waves x 32x32) ----------------
// R14-proven: grid 128x4 = 512 blocks = 2 blocks/CU (16 waves/CU), one round.

__global__ __launch_bounds__(512) void gemm_out_kernel(
    const u16* __restrict__ att, const u16* __restrict__ Wot,
    const float* __restrict__ bo, float* __restrict__ out) {
    __shared__ __align__(16) u16 Al[64 * 32];
    __shared__ __align__(16) u16 Bl[128 * 32];
    f32x4 acc[2][2];
#pragma unroll
    for (int mi = 0; mi < 2; ++mi)
#pragma unroll
        for (int ni = 0; ni < 2; ++ni)
#pragma unroll
            for (int e = 0; e < 4; ++e) acc[mi][ni][e] = 0.f;

    const int m0 = blockIdx.x * 64, n0 = blockIdx.y * 128;
    const int tid = threadIdx.x;
    const int lane = tid & 63;
    const int w = tid >> 6;              // 0..7
    const int wm = w >> 2, wn = w & 3;   // 2M x 4N, wave = 32x32
    const int lg = lane >> 4, lr = lane & 15;

    const int srow = lane >> 2;
    const int schunk = ((lane & 3) ^ ((lane >> 3) & 3)) * 8;
    const u16* ga = att + (size_t)(m0 + w * 16 + srow) * CH + schunk;
    const u16* gb = Wot + (size_t)(n0 + w * 16 + srow) * CH + schunk;
    const int rchunk = (lg ^ ((lr >> 1) & 3)) * 8;

    for (int k0 = 0; k0 < CH; k0 += 32) {
        __syncthreads();
        if (w < 4) gl16(ga + k0, Al + w * 512);
        gl16(gb + k0, Bl + w * 512);
        __syncthreads();
        bf16x8 af[2], bfr[2];
#pragma unroll
        for (int i = 0; i < 2; ++i) {
            af[i]  = *(const bf16x8*)(Al + (wm * 32 + i * 16 + lr) * 32 + rchunk);
            bfr[i] = *(const bf16x8*)(Bl + (wn * 32 + i * 16 + lr) * 32 + rchunk);
        }
#pragma unroll
        for (int mi = 0; mi < 2; ++mi)
#pragma unroll
            for (int ni = 0; ni < 2; ++ni)
                acc[mi][ni] = MFMA16(af[mi], bfr[ni], acc[mi][ni]);
    }

#pragma unroll
    for (int ni = 0; ni < 2; ++ni) {
        const int c = n0 + wn * 32 + ni * 16 + lr;
        const float bias = bo[c];
#pragma unroll
        for (int mi = 0; mi < 2; ++mi)
#pragma unroll
            for (int r = 0; r < 4; ++r) {
                const int row = m0 + wm * 32 + mi * 16 + lg * 4 + r;
                out[(size_t)row * CH + c] = acc[mi][ni][r] + bias;
            }
    }
}

// ---------------- flash attention: 4-wave additive s-split, 32x32 MFMA ----------------
// Swapped QK^T: S^T = mfma32(A=K, B=Q).  C/D: col=q=lane&31, row=s=(g&3)+8*(g>>2)+4h.
// m==0 softmax => partial (O, lsum) additive across waves; tree combine in LDS.
// K/V compacted + fragment-major => all frag loads are 1KB coalesced wave-loads.
// (256,4): ~52 VGPR + 32 AGPR unified budget; tighter pins collapse (R8 lesson).
// No setprio (R18: -1.6us, no wave role-split here).
__global__ __launch_bounds__(256, 4) void attn_kernel(
    const u16* __restrict__ q_ws, const u16* __restrict__ k_ws,
    const u16* __restrict__ v_t, u16* __restrict__ attout) {
    const int bid = blockIdx.x;
    const int xcd = bid & 7, idx = bid >> 3;
    const int bn = xcd + 8 * (idx >> 6);      // 4 bn per XCD -> K/V/Q L2-resident
    const int qb = 63 - (idx & 63);           // longest q-blocks first
    const int q0 = qb * 32;
    const int l = threadIdx.x & 63;
    const int w = threadIdx.x >> 6;
    const int ql = l & 31, h = l >> 5;

    const int t = q0 + ql;
    const int kct = kc_of(t);                 // per-lane causal boundary (compact idx)
    const int kcq0 = kc_of(q0);               // block-uniform
    const int kcmax = kc_of(q0 + 31);         // block-uniform
    const int ntc32 = (kcmax + 31) >> 5;

    const size_t baseq = (size_t)bn * CT * CD;
    const size_t basek = (size_t)bn * CT * CD;
    const size_t basev = (size_t)bn * CD * CT;

    // Q as B-operand: lane holds Q[q0+ql][16c + 8h + j]
    bf16x8 qf[4];
    {
        const u16* qp = q_ws + baseq + (size_t)t * CD + h * 8;
#pragma unroll
        for (int c = 0; c < 4; ++c) qf[c] = *(const bf16x8*)(qp + c * 16);
    }

    f32x16 oa[2];
#pragma unroll
    for (int dh = 0; dh < 2; ++dh)
#pragma unroll
        for (int e = 0; e < 16; ++e) oa[dh][e] = 0.f;
    float lsum = 0.f;

    for (int i32 = w; i32 < ntc32; i32 += 4) {
        const int s0h = i32 * 32;
        const bool needmask = (s0h + 31 >= kcq0);   // tail: per-element causal
        const u16* ktile = k_ws + basek + (size_t)i32 * 2048;
        const u16* vtile = v_t + basev + (size_t)i32 * 2048;

        // S^T = K · Q^T : A-frag = coalesced fragment-major load, B-frag = qf
        f32x16 sa;
#pragma unroll
        for (int e = 0; e < 16; ++e) sa[e] = 0.f;
#pragma unroll
        for (int c = 0; c < 4; ++c) {
            bf16x8 kf = *(const bf16x8*)(ktile + ((c * 2 + h) * 32 + ql) * 8);
            sa = MFMA32(kf, qf[c], sa);
        }

        // p = exp2(s'), per-lane lsum (no cross-lane ops)
        float pr[16];
        if (needmask) {
#pragma unroll
            for (int g = 0; g < 16; ++g) {
                const int roff = (g & 3) + 8 * (g >> 2);
                float e = __builtin_amdgcn_exp2f(sa[g]);
                e = (s0h + roff + 4 * h < kct) ? e : 0.f;
                lsum += e;
                pr[g] = e;
            }
        } else {
#pragma unroll
            for (int g = 0; g < 16; ++g) {
                float e = __builtin_amdgcn_exp2f(sa[g]);
                lsum += e;
                pr[g] = e;
            }
        }

        // Pack P to bf16 A-frags in-register (half-exchange via shfl_xor(32)+select)
#pragma unroll
        for (int kb = 0; kb < 2; ++kb) {
            const int g0 = kb * 8;
            unsigned int w0, w1, w2, w3;
            asm("v_cvt_pk_bf16_f32 %0, %1, %2" : "=v"(w0) : "v"(pr[g0 + 0]), "v"(pr[g0 + 1]));
            asm("v_cvt_pk_bf16_f32 %0, %1, %2" : "=v"(w1) : "v"(pr[g0 + 2]), "v"(pr[g0 + 3]));
            asm("v_cvt_pk_bf16_f32 %0, %1, %2" : "=v"(w2) : "v"(pr[g0 + 4]), "v"(pr[g0 + 5]));
            asm("v_cvt_pk_bf16_f32 %0, %1, %2" : "=v"(w3) : "v"(pr[g0 + 6]), "v"(pr[g0 + 7]));
            const unsigned int x0 = (unsigned int)__shfl_xor((int)w0, 32);
            const unsigned int x1 = (unsigned int)__shfl_xor((int)w1, 32);
            const unsigned int x2 = (unsigned int)__shfl_xor((int)w2, 32);
            const unsigned int x3 = (unsigned int)__shfl_xor((int)w3, 32);
            u32x4 fw;
            fw.x = h ? x2 : w0;
            fw.y = h ? x3 : w1;
            fw.z = h ? w2 : x0;
            fw.w = h ? w3 : x1;
            const bf16x8 pa = __builtin_bit_cast(bf16x8, fw);
#pragma unroll
            for (int dh = 0; dh < 2; ++dh) {
                bf16x8 vf = *(const bf16x8*)(vtile + (((dh * 2 + kb) * 2 + h) * 32 + ql) * 8);
                oa[dh] = MFMA32(pa, vf, oa[dh]);
            }
        }
    }

    // ---- additive tree combine across the 4 waves (2 buffers, 17.6 KB LDS) ----
    __shared__ float buf[2][64][33];
    __shared__ float lsp[4][64];
    __shared__ float lsf[32];

    lsp[w][l] = lsum;
    if (w >= 2) {
#pragma unroll
        for (int dh = 0; dh < 2; ++dh)
#pragma unroll
            for (int g = 0; g < 16; ++g)
                buf[w - 2][l][dh * 16 + g] = oa[dh][g];
    }
    __syncthreads();
    if (w < 2) {
#pragma unroll
        for (int dh = 0; dh < 2; ++dh)
#pragma unroll
            for (int g = 0; g < 16; ++g)
                oa[dh][g] += buf[w][l][dh * 16 + g];
    }
    if (threadIdx.x < 32) {
        const int r = threadIdx.x;
        float s = 0.f;
#pragma unroll
        for (int ww = 0; ww < 4; ++ww) s += lsp[ww][r] + lsp[ww][r + 32];
        lsf[r] = 1.f / s;
    }
    __syncthreads();
    if (w == 1) {
#pragma unroll
        for (int dh = 0; dh < 2; ++dh)
#pragma unroll
            for (int g = 0; g < 16; ++g)
                buf[0][l][dh * 16 + g] = oa[dh][g];
    }
    __syncthreads();
    if (w == 0) {
        const int b = bn >> 3, nh = bn & 7;
#pragma unroll
        for (int dh = 0; dh < 2; ++dh)
#pragma unroll
            for (int g = 0; g < 16; ++g) {
                const float s = oa[dh][g] + buf[0][l][dh * 16 + g];
                const int r = (g & 3) + 8 * (g >> 2) + 4 * h;
                attout[(size_t)(b * CT + q0 + r) * CH + nh * 64 + dh * 32 + ql] = f2bf(s * lsf[r]);
            }
    }
}

// ---------------- launcher ----------------

extern "C" void kernel_launch(void* const* d_in, const int* in_sizes, int n_in,
                              void* d_out, int out_size, void* d_ws, size_t ws_size,
                              hipStream_t stream) {
    const float* x  = (const float*)d_in[0];
    const float* Wq = (const float*)d_in[1];
    const float* bq = (const float*)d_in[2];
    const float* Wk = (const float*)d_in[3];
    const float* bk = (const float*)d_in[4];
    const float* Wv = (const float*)d_in[5];
    const float* bv = (const float*)d_in[6];
    const float* Wo = (const float*)d_in[7];
    const float* bo = (const float*)d_in[8];
    float* out = (float*)d_out;

    char* p = (char*)d_ws;
    u16* xb = (u16*)p;        p += (size_t)CM * CH * 2;        // 8 MB
    u16* Wt = (u16*)p;        p += (size_t)4 * CH * CH * 2;    // 2 MB
    float2* tab = (float2*)p; p += (size_t)CT * (CH / 2) * 8;  // 4 MB
    u16* q_ws = (u16*)p;      p += (size_t)CM * CH * 2;        // 8 MB
    u16* k_ws = (u16*)p;      p += (size_t)CM * CH * 2;        // 8 MB (frag-major tiles)
    u16* v_t  = (u16*)p;      p += (size_t)CM * CH * 2;        // 8 MB (frag-major tiles)
    u16* attout = (u16*)p;    p += (size_t)CM * CH * 2;        // 8 MB

    prep_kernel<<<dim3(5120), 256, 0, stream>>>(x, xb, Wq, Wk, Wv, Wo, Wt, tab);
    gemm_qkv_kernel<<<dim3(CM / 128, (3 * CH) / 192), 768, 0, stream>>>(
        xb, Wt, bq, bk, bv, tab, q_ws, k_ws, v_t);
    attn_kernel<<<dim3(2048), 256, 0, stream>>>(q_ws, k_ws, v_t, attout);
    gemm_out_kernel<<<dim3(CM / 64, CH / 128), 512, 0, stream>>>(
        attout, Wt + (size_t)3 * CH * CH, bo, out);
}

// Round 21
// 80.398 us; speedup vs baseline: 1.2239x; 1.2239x over previous
//
#include <hip/hip_runtime.h>

typedef unsigned short u16;
typedef __attribute__((ext_vector_type(8))) short bf16x8;
typedef __attribute__((ext_vector_type(8))) unsigned short u16x8;
typedef __attribute__((ext_vector_type(4))) float f32x4;
typedef __attribute__((ext_vector_type(16))) float f32x16;
typedef __attribute__((ext_vector_type(4))) unsigned int u32x4;

#define MFMA16(a, b, c) __builtin_amdgcn_mfma_f32_16x16x32_bf16((a), (b), (c), 0, 0, 0)
#define MFMA32(a, b, c) __builtin_amdgcn_mfma_f32_32x32x16_bf16((a), (b), (c), 0, 0, 0)

static constexpr int CB = 4, CT = 2048, CH = 512, CN = 8, CD = 64;
static constexpr int CM = CB * CT;  // 8192 rows

__device__ __forceinline__ u16 f2bf(float f) {
    union { float f; unsigned int i; } v; v.f = f;
    unsigned int r = v.i + 0x7FFFu + ((v.i >> 16) & 1u);
    return (u16)(r >> 16);
}

// kept-count: # of unmasked cols s in [0, t]  (masked: s>=4 && s%3==1)
__device__ __forceinline__ int kc_of(int t) {
    return t + 1 - ((t >= 4) ? ((t - 1) / 3) : 0);
}

// async global->LDS, 16B per lane (wave-uniform LDS base + lane*16)
__device__ __forceinline__ void gl16(const u16* g, u16* l) {
    __builtin_amdgcn_global_load_lds(
        (const __attribute__((address_space(1))) void*)g,
        (__attribute__((address_space(3))) void*)l, 16, 0, 0);
}

// ---------------- fused prep kernel (R15-verified, R17-isolated -3.3us) ----------------
// blocks [0,1024): Wt transpose+cvt; [1024,3072): rope table; [3072,5120): x->bf16.
__global__ __launch_bounds__(256) void prep_kernel(
    const float* __restrict__ x, u16* __restrict__ xb,
    const float* __restrict__ Wq, const float* __restrict__ Wk,
    const float* __restrict__ Wv, const float* __restrict__ Wo,
    u16* __restrict__ Wt, float2* __restrict__ tab) {
    const int blk = blockIdx.x;
    if (blk < 1024) {
        // Wt[w][n][k] = bf16(W_w[k][n]) — flat-256 reindexed transpose
        __shared__ float tile[32][33];
        const int z = blk >> 8, rem = blk & 255;
        const int n0 = (rem & 15) * 32, k0 = (rem >> 4) * 32;
        const float* W = (z == 0) ? Wq : (z == 1) ? Wk : (z == 2) ? Wv : Wo;
        u16* dst = Wt + (size_t)z * CH * CH;
        const int tx = threadIdx.x & 31, ty = threadIdx.x >> 5;  // 32 x 8
        for (int j = 0; j < 32; j += 8)
            tile[ty + j][tx] = W[(size_t)(k0 + ty + j) * CH + n0 + tx];
        __syncthreads();
        for (int j = 0; j < 32; j += 8)
            dst[(size_t)(n0 + ty + j) * CH + k0 + tx] = f2bf(tile[tx][ty + j]);
    } else if (blk < 3072) {
        const int i = (blk - 1024) * 256 + threadIdx.x;  // i < CT*256 exactly
        const int t = i >> 8, h = i & 255;
        float inv = exp2f(-(float)h * (13.287712379549449f / 256.0f));
        float s, c;
        sincosf((float)t * inv, &s, &c);
        tab[i] = make_float2(c, s);
    } else {
        const int n4 = CM * CH / 4;
        const float4* x4 = (const float4*)x;
        for (int i = (blk - 3072) * 256 + threadIdx.x; i < n4; i += 2048 * 256) {
            float4 v = x4[i];
            unsigned long long pack = (unsigned long long)f2bf(v.x)
                                    | ((unsigned long long)f2bf(v.y) << 16)
                                    | ((unsigned long long)f2bf(v.z) << 32)
                                    | ((unsigned long long)f2bf(v.w) << 48);
            ((unsigned long long*)xb)[i] = pack;
        }
    }
}

// ---------------- qkv GEMM main loop (128x128 tile, BK=32, 8 waves x 64x32) ----------------
// R11/R14-proven structure: global_load_lds width-16 staging into LINEAR [128][32] u16 LDS
// with 16B-chunk XOR swizzle (rule #21): LDS(row, s) holds global chunk s ^ ((row>>1)&3).
// Tile-shape search closed: 192/96/256-variants (R13/15/16/20) all regressed — 2 blocks/CU
// cross-block overlap beats tail elimination for this short-K latency-bound GEMM.

__device__ __forceinline__ void gemm_bt_main(const u16* __restrict__ A, const u16* __restrict__ Bt,
                                             int m0, int n0, f32x4 acc[4][2]) {
    __shared__ __align__(16) u16 Al[128 * 32];
    __shared__ __align__(16) u16 Bl[128 * 32];
    const int tid = threadIdx.x;
    const int lane = tid & 63;
    const int w = tid >> 6;              // 0..7
    const int wm = w >> 2, wn = w & 3;   // 2 x 4
    const int lg = lane >> 4, lr = lane & 15;

    // staging: wave w covers rows [w*16, w*16+16) of A and B (1 gl16 each = 1KB).
    // lane l -> row w*16 + (l>>2), chunk (l&3); source chunk = (l&3) ^ ((l>>3)&3).
    const int srow = w * 16 + (lane >> 2);
    const int schunk = ((lane & 3) ^ ((lane >> 3) & 3)) * 8;
    const u16* ga = A  + (size_t)(m0 + srow) * CH + schunk;
    const u16* gb = Bt + (size_t)(n0 + srow) * CH + schunk;
    u16* lA0 = Al + w * 512;  // wave-uniform base; HW adds lane*16B
    u16* lB0 = Bl + w * 512;

    // read swizzle term: chunk = lg ^ ((lr>>1)&3)
    const int rchunk = (lg ^ ((lr >> 1) & 3)) * 8;

    for (int k0 = 0; k0 < CH; k0 += 32) {
        __syncthreads();
        gl16(ga + k0, lA0);
        gl16(gb + k0, lB0);
        __syncthreads();
        bf16x8 af[4], bfr[2];
#pragma unroll
        for (int i = 0; i < 4; ++i)
            af[i] = *(const bf16x8*)(Al + (wm * 64 + i * 16 + lr) * 32 + rchunk);
#pragma unroll
        for (int i = 0; i < 2; ++i)
            bfr[i] = *(const bf16x8*)(Bl + (wn * 32 + i * 16 + lr) * 32 + rchunk);
#pragma unroll
        for (int mi = 0; mi < 4; ++mi)
#pragma unroll
            for (int ni = 0; ni < 2; ++ni)
                acc[mi][ni] = MFMA16(af[mi], bfr[ni], acc[mi][ni]);
    }
}

// QKV GEMM epilogue: +bias, RoPE(q,k), q *= 0.125*log2(e) (exp2-folded softmax scale),
// k/v stored COMPACTED (masked cols dropped) in FRAGMENT-MAJOR per-32-s-tile layout:
//   K: [bn][tile][c][h][ql=s&31][j=8]   (lane-contiguous attn A-frag loads)
//   V: [bn][tile][dh][kb][h][ql=d&31][j=8]
__global__ __launch_bounds__(512) void gemm_qkv_kernel(
    const u16* __restrict__ xb, const u16* __restrict__ Wt,
    const float* __restrict__ bq, const float* __restrict__ bk, const float* __restrict__ bv,
    const float2* __restrict__ tab,
    u16* __restrict__ q_ws, u16* __restrict__ k_ws, u16* __restrict__ v_t) {
    f32x4 acc[4][2];
#pragma unroll
    for (int mi = 0; mi < 4; ++mi)
#pragma unroll
        for (int ni = 0; ni < 2; ++ni)
#pragma unroll
            for (int e = 0; e < 4; ++e) acc[mi][ni][e] = 0.f;

    const int m0 = blockIdx.x * 128, n0 = blockIdx.y * 128;
    gemm_bt_main(xb, Wt, m0, n0, acc);

    const int lane = threadIdx.x & 63;
    const int w = threadIdx.x >> 6, wm = w >> 2, wn = w & 3;
    const int lg = lane >> 4, lr = lane & 15;
    const int seg = n0 >> 9;  // 0=q 1=k 2=v (uniform per block: 128-tiles don't straddle)
    const float* bias_p = (seg == 0) ? bq : (seg == 1) ? bk : bv;

#pragma unroll
    for (int ni = 0; ni < 2; ++ni) {
        const int c = n0 + wn * 32 + ni * 16 + lr;
        const int cc = c & 511;
        const int nh = cc >> 6, d = cc & 63;
        const float bias = bias_p[cc];
#pragma unroll
        for (int mi = 0; mi < 4; ++mi) {
#pragma unroll
            for (int r = 0; r < 4; ++r) {
                const int row = m0 + wm * 64 + mi * 16 + lg * 4 + r;
                const int b = row >> 11, t = row & 2047;
                float val = acc[mi][ni][r] + bias;
                if (seg < 2) {  // RoPE: pair (c, c^1) lives in lane^1
                    float2 cs = tab[t * 256 + (cc >> 1)];
                    float partner = __shfl_xor(val, 1);
                    val = val * cs.x + ((lane & 1) ? partner * cs.y : -partner * cs.y);
                }
                if (seg == 0) {
                    val *= 0.18033688011112f;  // (1/8)*log2(e): softmax via exp2
                    q_ws[(size_t)((b * CN + nh) * CT + t) * CD + d] = f2bf(val);
                } else {
                    const bool msk = (t >= 4) && (t % 3 == 1);
                    if (!msk) {
                        const int ci = t - ((t >= 4) ? ((t - 1) / 3) : 0);
                        const int tile = ci >> 5, sl = ci & 31;
                        const size_t tb = (size_t)(b * CN + nh) * CT * CD + (size_t)tile * 2048;
                        if (seg == 1) {
                            const int cF = d >> 4, hF = (d >> 3) & 1, jF = d & 7;
                            k_ws[tb + ((cF * 2 + hF) * 32 + sl) * 8 + jF] = f2bf(val);
                        } else {
                            const int kbF = sl >> 4, hF = (sl >> 3) & 1, jF = sl & 7;
                            const int dhF = d >> 5, qlF = d & 31;
                            v_t[tb + (((dhF * 2 + kbF) * 2 + hF) * 32 + qlF) * 8 + jF] = f2bf(val);
                        }
                    }
                }
            }
        }
    }
}

// ---------------- out GEMM (64x128 tile, BK=32, 8 waves x 32x32) ----------------
// R14-proven: grid 128x4 = 512 blocks = 2 blocks/CU (16 waves/CU), one round.

__global__ __launch_bounds__(512) void gemm_out_kernel(
    const u16* __restrict__ att, const u16* __restrict__ Wot,
    const float* __restrict__ bo, float* __restrict__ out) {
    __shared__ __align__(16) u16 Al[64 * 32];
    __shared__ __align__(16) u16 Bl[128 * 32];
    f32x4 acc[2][2];
#pragma unroll
    for (int mi = 0; mi < 2; ++mi)
#pragma unroll
        for (int ni = 0; ni < 2; ++ni)
#pragma unroll
            for (int e = 0; e < 4; ++e) acc[mi][ni][e] = 0.f;

    const int m0 = blockIdx.x * 64, n0 = blockIdx.y * 128;
    const int tid = threadIdx.x;
    const int lane = tid & 63;
    const int w = tid >> 6;              // 0..7
    const int wm = w >> 2, wn = w & 3;   // 2M x 4N, wave = 32x32
    const int lg = lane >> 4, lr = lane & 15;

    const int srow = lane >> 2;
    const int schunk = ((lane & 3) ^ ((lane >> 3) & 3)) * 8;
    const u16* ga = att + (size_t)(m0 + w * 16 + srow) * CH + schunk;
    const u16* gb = Wot + (size_t)(n0 + w * 16 + srow) * CH + schunk;
    const int rchunk = (lg ^ ((lr >> 1) & 3)) * 8;

    for (int k0 = 0; k0 < CH; k0 += 32) {
        __syncthreads();
        if (w < 4) gl16(ga + k0, Al + w * 512);
        gl16(gb + k0, Bl + w * 512);
        __syncthreads();
        bf16x8 af[2], bfr[2];
#pragma unroll
        for (int i = 0; i < 2; ++i) {
            af[i]  = *(const bf16x8*)(Al + (wm * 32 + i * 16 + lr) * 32 + rchunk);
            bfr[i] = *(const bf16x8*)(Bl + (wn * 32 + i * 16 + lr) * 32 + rchunk);
        }
#pragma unroll
        for (int mi = 0; mi < 2; ++mi)
#pragma unroll
            for (int ni = 0; ni < 2; ++ni)
                acc[mi][ni] = MFMA16(af[mi], bfr[ni], acc[mi][ni]);
    }

#pragma unroll
    for (int ni = 0; ni < 2; ++ni) {
        const int c = n0 + wn * 32 + ni * 16 + lr;
        const float bias = bo[c];
#pragma unroll
        for (int mi = 0; mi < 2; ++mi)
#pragma unroll
            for (int r = 0; r < 4; ++r) {
                const int row = m0 + wm * 32 + mi * 16 + lg * 4 + r;
                out[(size_t)row * CH + c] = acc[mi][ni][r] + bias;
            }
    }
}

// ---------------- flash attention: 4-wave additive s-split, 32x32 MFMA ----------------
// Swapped QK^T: S^T = mfma32(A=K, B=Q).  C/D: col=q=lane&31, row=s=(g&3)+8*(g>>2)+4h.
// m==0 softmax => partial (O, lsum) additive across waves; tree combine in LDS.
// K/V compacted + fragment-major => all frag loads are 1KB coalesced wave-loads.
// (256,4): ~52 VGPR + 32 AGPR unified budget; tighter pins collapse (R8 lesson).
// No setprio (R18: -1.6us, no wave role-split here).
__global__ __launch_bounds__(256, 4) void attn_kernel(
    const u16* __restrict__ q_ws, const u16* __restrict__ k_ws,
    const u16* __restrict__ v_t, u16* __restrict__ attout) {
    const int bid = blockIdx.x;
    const int xcd = bid & 7, idx = bid >> 3;
    const int bn = xcd + 8 * (idx >> 6);      // 4 bn per XCD -> K/V/Q L2-resident
    const int qb = 63 - (idx & 63);           // longest q-blocks first
    const int q0 = qb * 32;
    const int l = threadIdx.x & 63;
    const int w = threadIdx.x >> 6;
    const int ql = l & 31, h = l >> 5;

    const int t = q0 + ql;
    const int kct = kc_of(t);                 // per-lane causal boundary (compact idx)
    const int kcq0 = kc_of(q0);               // block-uniform
    const int kcmax = kc_of(q0 + 31);         // block-uniform
    const int ntc32 = (kcmax + 31) >> 5;

    const size_t baseq = (size_t)bn * CT * CD;
    const size_t basek = (size_t)bn * CT * CD;
    const size_t basev = (size_t)bn * CD * CT;

    // Q as B-operand: lane holds Q[q0+ql][16c + 8h + j]
    bf16x8 qf[4];
    {
        const u16* qp = q_ws + baseq + (size_t)t * CD + h * 8;
#pragma unroll
        for (int c = 0; c < 4; ++c) qf[c] = *(const bf16x8*)(qp + c * 16);
    }

    f32x16 oa[2];
#pragma unroll
    for (int dh = 0; dh < 2; ++dh)
#pragma unroll
        for (int e = 0; e < 16; ++e) oa[dh][e] = 0.f;
    float lsum = 0.f;

    for (int i32 = w; i32 < ntc32; i32 += 4) {
        const int s0h = i32 * 32;
        const bool needmask = (s0h + 31 >= kcq0);   // tail: per-element causal
        const u16* ktile = k_ws + basek + (size_t)i32 * 2048;
        const u16* vtile = v_t + basev + (size_t)i32 * 2048;

        // S^T = K · Q^T : A-frag = coalesced fragment-major load, B-frag = qf
        f32x16 sa;
#pragma unroll
        for (int e = 0; e < 16; ++e) sa[e] = 0.f;
#pragma unroll
        for (int c = 0; c < 4; ++c) {
            bf16x8 kf = *(const bf16x8*)(ktile + ((c * 2 + h) * 32 + ql) * 8);
            sa = MFMA32(kf, qf[c], sa);
        }

        // p = exp2(s'), per-lane lsum (no cross-lane ops)
        float pr[16];
        if (needmask) {
#pragma unroll
            for (int g = 0; g < 16; ++g) {
                const int roff = (g & 3) + 8 * (g >> 2);
                float e = __builtin_amdgcn_exp2f(sa[g]);
                e = (s0h + roff + 4 * h < kct) ? e : 0.f;
                lsum += e;
                pr[g] = e;
            }
        } else {
#pragma unroll
            for (int g = 0; g < 16; ++g) {
                float e = __builtin_amdgcn_exp2f(sa[g]);
                lsum += e;
                pr[g] = e;
            }
        }

        // Pack P to bf16 A-frags in-register (half-exchange via shfl_xor(32)+select)
#pragma unroll
        for (int kb = 0; kb < 2; ++kb) {
            const int g0 = kb * 8;
            unsigned int w0, w1, w2, w3;
            asm("v_cvt_pk_bf16_f32 %0, %1, %2" : "=v"(w0) : "v"(pr[g0 + 0]), "v"(pr[g0 + 1]));
            asm("v_cvt_pk_bf16_f32 %0, %1, %2" : "=v"(w1) : "v"(pr[g0 + 2]), "v"(pr[g0 + 3]));
            asm("v_cvt_pk_bf16_f32 %0, %1, %2" : "=v"(w2) : "v"(pr[g0 + 4]), "v"(pr[g0 + 5]));
            asm("v_cvt_pk_bf16_f32 %0, %1, %2" : "=v"(w3) : "v"(pr[g0 + 6]), "v"(pr[g0 + 7]));
            const unsigned int x0 = (unsigned int)__shfl_xor((int)w0, 32);
            const unsigned int x1 = (unsigned int)__shfl_xor((int)w1, 32);
            const unsigned int x2 = (unsigned int)__shfl_xor((int)w2, 32);
            const unsigned int x3 = (unsigned int)__shfl_xor((int)w3, 32);
            u32x4 fw;
            fw.x = h ? x2 : w0;
            fw.y = h ? x3 : w1;
            fw.z = h ? w2 : x0;
            fw.w = h ? w3 : x1;
            const bf16x8 pa = __builtin_bit_cast(bf16x8, fw);
#pragma unroll
            for (int dh = 0; dh < 2; ++dh) {
                bf16x8 vf = *(const bf16x8*)(vtile + (((dh * 2 + kb) * 2 + h) * 32 + ql) * 8);
                oa[dh] = MFMA32(pa, vf, oa[dh]);
            }
        }
    }

    // ---- additive tree combine across the 4 waves (2 buffers, 17.6 KB LDS) ----
    __shared__ float buf[2][64][33];
    __shared__ float lsp[4][64];
    __shared__ float lsf[32];

    lsp[w][l] = lsum;
    if (w >= 2) {
#pragma unroll
        for (int dh = 0; dh < 2; ++dh)
#pragma unroll
            for (int g = 0; g < 16; ++g)
                buf[w - 2][l][dh * 16 + g] = oa[dh][g];
    }
    __syncthreads();
    if (w < 2) {
#pragma unroll
        for (int dh = 0; dh < 2; ++dh)
#pragma unroll
            for (int g = 0; g < 16; ++g)
                oa[dh][g] += buf[w][l][dh * 16 + g];
    }
    if (threadIdx.x < 32) {
        const int r = threadIdx.x;
        float s = 0.f;
#pragma unroll
        for (int ww = 0; ww < 4; ++ww) s += lsp[ww][r] + lsp[ww][r + 32];
        lsf[r] = 1.f / s;
    }
    __syncthreads();
    if (w == 1) {
#pragma unroll
        for (int dh = 0; dh < 2; ++dh)
#pragma unroll
            for (int g = 0; g < 16; ++g)
                buf[0][l][dh * 16 + g] = oa[dh][g];
    }
    __syncthreads();
    if (w == 0) {
        const int b = bn >> 3, nh = bn & 7;
#pragma unroll
        for (int dh = 0; dh < 2; ++dh)
#pragma unroll
            for (int g = 0; g < 16; ++g) {
                const float s = oa[dh][g] + buf[0][l][dh * 16 + g];
                const int r = (g & 3) + 8 * (g >> 2) + 4 * h;
                attout[(size_t)(b * CT + q0 + r) * CH + nh * 64 + dh * 32 + ql] = f2bf(s * lsf[r]);
            }
    }
}

// ---------------- launcher ----------------

extern "C" void kernel_launch(void* const* d_in, const int* in_sizes, int n_in,
                              void* d_out, int out_size, void* d_ws, size_t ws_size,
                              hipStream_t stream) {
    const float* x  = (const float*)d_in[0];
    const float* Wq = (const float*)d_in[1];
    const float* bq = (const float*)d_in[2];
    const float* Wk = (const float*)d_in[3];
    const float* bk = (const float*)d_in[4];
    const float* Wv = (const float*)d_in[5];
    const float* bv = (const float*)d_in[6];
    const float* Wo = (const float*)d_in[7];
    const float* bo = (const float*)d_in[8];
    float* out = (float*)d_out;

    char* p = (char*)d_ws;
    u16* xb = (u16*)p;        p += (size_t)CM * CH * 2;        // 8 MB
    u16* Wt = (u16*)p;        p += (size_t)4 * CH * CH * 2;    // 2 MB
    float2* tab = (float2*)p; p += (size_t)CT * (CH / 2) * 8;  // 4 MB
    u16* q_ws = (u16*)p;      p += (size_t)CM * CH * 2;        // 8 MB
    u16* k_ws = (u16*)p;      p += (size_t)CM * CH * 2;        // 8 MB (frag-major tiles)
    u16* v_t  = (u16*)p;      p += (size_t)CM * CH * 2;        // 8 MB (frag-major tiles)
    u16* attout = (u16*)p;    p += (size_t)CM * CH * 2;        // 8 MB

    prep_kernel<<<dim3(5120), 256, 0, stream>>>(x, xb, Wq, Wk, Wv, Wo, Wt, tab);
    gemm_qkv_kernel<<<dim3(CM / 128, (3 * CH) / 128), 512, 0, stream>>>(
        xb, Wt, bq, bk, bv, tab, q_ws, k_ws, v_t);
    attn_kernel<<<dim3(2048), 256, 0, stream>>>(q_ws, k_ws, v_t, attout);
    gemm_out_kernel<<<dim3(CM / 64, CH / 128), 512, 0, stream>>>(
        attout, Wt + (size_t)3 * CH * CH, bo, out);
}

// Round 22
// 74.497 us; speedup vs baseline: 1.3209x; 1.0792x over previous
//
#include <hip/hip_runtime.h>

typedef unsigned short u16;
typedef __attribute__((ext_vector_type(8))) short bf16x8;
typedef __attribute__((ext_vector_type(8))) unsigned short u16x8;
typedef __attribute__((ext_vector_type(4))) float f32x4;
typedef __attribute__((ext_vector_type(16))) float f32x16;
typedef __attribute__((ext_vector_type(4))) unsigned int u32x4;

#define MFMA16(a, b, c) __builtin_amdgcn_mfma_f32_16x16x32_bf16((a), (b), (c), 0, 0, 0)
#define MFMA32(a, b, c) __builtin_amdgcn_mfma_f32_32x32x16_bf16((a), (b), (c), 0, 0, 0)

static constexpr int CB = 4, CT = 2048, CH = 512, CN = 8, CD = 64;
static constexpr int CM = CB * CT;  // 8192 rows

__device__ __forceinline__ u16 f2bf(float f) {
    union { float f; unsigned int i; } v; v.f = f;
    unsigned int r = v.i + 0x7FFFu + ((v.i >> 16) & 1u);
    return (u16)(r >> 16);
}

// kept-count: # of unmasked cols s in [0, t]  (masked: s>=4 && s%3==1)
__device__ __forceinline__ int kc_of(int t) {
    return t + 1 - ((t >= 4) ? ((t - 1) / 3) : 0);
}

// async global->LDS, 16B per lane (wave-uniform LDS base + lane*16)
__device__ __forceinline__ void gl16(const u16* g, u16* l) {
    __builtin_amdgcn_global_load_lds(
        (const __attribute__((address_space(1))) void*)g,
        (__attribute__((address_space(3))) void*)l, 16, 0, 0);
}

// ---------------- fused prep kernel (R15-verified, R17-isolated -3.3us) ----------------
// blocks [0,1024): Wt transpose+cvt; [1024,3072): rope table; [3072,5120): x->bf16.
__global__ __launch_bounds__(256) void prep_kernel(
    const float* __restrict__ x, u16* __restrict__ xb,
    const float* __restrict__ Wq, const float* __restrict__ Wk,
    const float* __restrict__ Wv, const float* __restrict__ Wo,
    u16* __restrict__ Wt, float2* __restrict__ tab) {
    const int blk = blockIdx.x;
    if (blk < 1024) {
        // Wt[w][n][k] = bf16(W_w[k][n]) — flat-256 reindexed transpose
        __shared__ float tile[32][33];
        const int z = blk >> 8, rem = blk & 255;
        const int n0 = (rem & 15) * 32, k0 = (rem >> 4) * 32;
        const float* W = (z == 0) ? Wq : (z == 1) ? Wk : (z == 2) ? Wv : Wo;
        u16* dst = Wt + (size_t)z * CH * CH;
        const int tx = threadIdx.x & 31, ty = threadIdx.x >> 5;  // 32 x 8
        for (int j = 0; j < 32; j += 8)
            tile[ty + j][tx] = W[(size_t)(k0 + ty + j) * CH + n0 + tx];
        __syncthreads();
        for (int j = 0; j < 32; j += 8)
            dst[(size_t)(n0 + ty + j) * CH + k0 + tx] = f2bf(tile[tx][ty + j]);
    } else if (blk < 3072) {
        const int i = (blk - 1024) * 256 + threadIdx.x;  // i < CT*256 exactly
        const int t = i >> 8, h = i & 255;
        float inv = exp2f(-(float)h * (13.287712379549449f / 256.0f));
        float s, c;
        sincosf((float)t * inv, &s, &c);
        tab[i] = make_float2(c, s);
    } else {
        const int n4 = CM * CH / 4;
        const float4* x4 = (const float4*)x;
        for (int i = (blk - 3072) * 256 + threadIdx.x; i < n4; i += 2048 * 256) {
            float4 v = x4[i];
            unsigned long long pack = (unsigned long long)f2bf(v.x)
                                    | ((unsigned long long)f2bf(v.y) << 16)
                                    | ((unsigned long long)f2bf(v.z) << 32)
                                    | ((unsigned long long)f2bf(v.w) << 48);
            ((unsigned long long*)xb)[i] = pack;
        }
    }
}

// ---------------- qkv GEMM main loop (128x128 tile, BK=32, 8 waves x 64x32) ----------------
// R11/R14-proven structure: global_load_lds width-16 staging into LINEAR [128][32] u16 LDS
// with 16B-chunk XOR swizzle (rule #21): LDS(row, s) holds global chunk s ^ ((row>>1)&3).
// Tile-shape search closed: 192/96/256-variants (R13/15/16/20) all regressed — 2 blocks/CU
// cross-block overlap beats tail elimination for this short-K latency-bound GEMM.

__device__ __forceinline__ void gemm_bt_main(const u16* __restrict__ A, const u16* __restrict__ Bt,
                                             int m0, int n0, f32x4 acc[4][2]) {
    __shared__ __align__(16) u16 Al[128 * 32];
    __shared__ __align__(16) u16 Bl[128 * 32];
    const int tid = threadIdx.x;
    const int lane = tid & 63;
    const int w = tid >> 6;              // 0..7
    const int wm = w >> 2, wn = w & 3;   // 2 x 4
    const int lg = lane >> 4, lr = lane & 15;

    // staging: wave w covers rows [w*16, w*16+16) of A and B (1 gl16 each = 1KB).
    // lane l -> row w*16 + (l>>2), chunk (l&3); source chunk = (l&3) ^ ((l>>3)&3).
    const int srow = w * 16 + (lane >> 2);
    const int schunk = ((lane & 3) ^ ((lane >> 3) & 3)) * 8;
    const u16* ga = A  + (size_t)(m0 + srow) * CH + schunk;
    const u16* gb = Bt + (size_t)(n0 + srow) * CH + schunk;
    u16* lA0 = Al + w * 512;  // wave-uniform base; HW adds lane*16B
    u16* lB0 = Bl + w * 512;

    // read swizzle term: chunk = lg ^ ((lr>>1)&3)
    const int rchunk = (lg ^ ((lr >> 1) & 3)) * 8;

    for (int k0 = 0; k0 < CH; k0 += 32) {
        __syncthreads();
        gl16(ga + k0, lA0);
        gl16(gb + k0, lB0);
        __syncthreads();
        bf16x8 af[4], bfr[2];
#pragma unroll
        for (int i = 0; i < 4; ++i)
            af[i] = *(const bf16x8*)(Al + (wm * 64 + i * 16 + lr) * 32 + rchunk);
#pragma unroll
        for (int i = 0; i < 2; ++i)
            bfr[i] = *(const bf16x8*)(Bl + (wn * 32 + i * 16 + lr) * 32 + rchunk);
#pragma unroll
        for (int mi = 0; mi < 4; ++mi)
#pragma unroll
            for (int ni = 0; ni < 2; ++ni)
                acc[mi][ni] = MFMA16(af[mi], bfr[ni], acc[mi][ni]);
    }
}

// QKV GEMM epilogue: +bias, RoPE(q,k), q *= 0.125*log2(e) (exp2-folded softmax scale),
// k/v stored COMPACTED (masked cols dropped) in FRAGMENT-MAJOR per-32-s-tile layout:
//   K: [bn][tile][c][h][ql=s&31][j=8]   (lane-contiguous attn A-frag loads)
//   V: [bn][tile][dh][kb][h][ql=d&31][j=8]
__global__ __launch_bounds__(512) void gemm_qkv_kernel(
    const u16* __restrict__ xb, const u16* __restrict__ Wt,
    const float* __restrict__ bq, const float* __restrict__ bk, const float* __restrict__ bv,
    const float2* __restrict__ tab,
    u16* __restrict__ q_ws, u16* __restrict__ k_ws, u16* __restrict__ v_t) {
    f32x4 acc[4][2];
#pragma unroll
    for (int mi = 0; mi < 4; ++mi)
#pragma unroll
        for (int ni = 0; ni < 2; ++ni)
#pragma unroll
            for (int e = 0; e < 4; ++e) acc[mi][ni][e] = 0.f;

    const int m0 = blockIdx.x * 128, n0 = blockIdx.y * 128;
    gemm_bt_main(xb, Wt, m0, n0, acc);

    const int lane = threadIdx.x & 63;
    const int w = threadIdx.x >> 6, wm = w >> 2, wn = w & 3;
    const int lg = lane >> 4, lr = lane & 15;
    const int seg = n0 >> 9;  // 0=q 1=k 2=v (uniform per block: 128-tiles don't straddle)
    const float* bias_p = (seg == 0) ? bq : (seg == 1) ? bk : bv;

#pragma unroll
    for (int ni = 0; ni < 2; ++ni) {
        const int c = n0 + wn * 32 + ni * 16 + lr;
        const int cc = c & 511;
        const int nh = cc >> 6, d = cc & 63;
        const float bias = bias_p[cc];
#pragma unroll
        for (int mi = 0; mi < 4; ++mi) {
#pragma unroll
            for (int r = 0; r < 4; ++r) {
                const int row = m0 + wm * 64 + mi * 16 + lg * 4 + r;
                const int b = row >> 11, t = row & 2047;
                float val = acc[mi][ni][r] + bias;
                if (seg < 2) {  // RoPE: pair (c, c^1) lives in lane^1
                    float2 cs = tab[t * 256 + (cc >> 1)];
                    float partner = __shfl_xor(val, 1);
                    val = val * cs.x + ((lane & 1) ? partner * cs.y : -partner * cs.y);
                }
                if (seg == 0) {
                    val *= 0.18033688011112f;  // (1/8)*log2(e): softmax via exp2
                    q_ws[(size_t)((b * CN + nh) * CT + t) * CD + d] = f2bf(val);
                } else {
                    const bool msk = (t >= 4) && (t % 3 == 1);
                    if (!msk) {
                        const int ci = t - ((t >= 4) ? ((t - 1) / 3) : 0);
                        const int tile = ci >> 5, sl = ci & 31;
                        const size_t tb = (size_t)(b * CN + nh) * CT * CD + (size_t)tile * 2048;
                        if (seg == 1) {
                            const int cF = d >> 4, hF = (d >> 3) & 1, jF = d & 7;
                            k_ws[tb + ((cF * 2 + hF) * 32 + sl) * 8 + jF] = f2bf(val);
                        } else {
                            const int kbF = sl >> 4, hF = (sl >> 3) & 1, jF = sl & 7;
                            const int dhF = d >> 5, qlF = d & 31;
                            v_t[tb + (((dhF * 2 + kbF) * 2 + hF) * 32 + qlF) * 8 + jF] = f2bf(val);
                        }
                    }
                }
            }
        }
    }
}

// ---------------- out GEMM (64x128 tile, BK=32, 8 waves x 32x32) ----------------
// R14-proven: grid 128x4 = 512 blocks = 2 blocks/CU (16 waves/CU), one round.

__global__ __launch_bounds__(512) void gemm_out_kernel(
    const u16* __restrict__ att, const u16* __restrict__ Wot,
    const float* __restrict__ bo, float* __restrict__ out) {
    __shared__ __align__(16) u16 Al[64 * 32];
    __shared__ __align__(16) u16 Bl[128 * 32];
    f32x4 acc[2][2];
#pragma unroll
    for (int mi = 0; mi < 2; ++mi)
#pragma unroll
        for (int ni = 0; ni < 2; ++ni)
#pragma unroll
            for (int e = 0; e < 4; ++e) acc[mi][ni][e] = 0.f;

    const int m0 = blockIdx.x * 64, n0 = blockIdx.y * 128;
    const int tid = threadIdx.x;
    const int lane = tid & 63;
    const int w = tid >> 6;              // 0..7
    const int wm = w >> 2, wn = w & 3;   // 2M x 4N, wave = 32x32
    const int lg = lane >> 4, lr = lane & 15;

    const int srow = lane >> 2;
    const int schunk = ((lane & 3) ^ ((lane >> 3) & 3)) * 8;
    const u16* ga = att + (size_t)(m0 + w * 16 + srow) * CH + schunk;
    const u16* gb = Wot + (size_t)(n0 + w * 16 + srow) * CH + schunk;
    const int rchunk = (lg ^ ((lr >> 1) & 3)) * 8;

    for (int k0 = 0; k0 < CH; k0 += 32) {
        __syncthreads();
        if (w < 4) gl16(ga + k0, Al + w * 512);
        gl16(gb + k0, Bl + w * 512);
        __syncthreads();
        bf16x8 af[2], bfr[2];
#pragma unroll
        for (int i = 0; i < 2; ++i) {
            af[i]  = *(const bf16x8*)(Al + (wm * 32 + i * 16 + lr) * 32 + rchunk);
            bfr[i] = *(const bf16x8*)(Bl + (wn * 32 + i * 16 + lr) * 32 + rchunk);
        }
#pragma unroll
        for (int mi = 0; mi < 2; ++mi)
#pragma unroll
            for (int ni = 0; ni < 2; ++ni)
                acc[mi][ni] = MFMA16(af[mi], bfr[ni], acc[mi][ni]);
    }

#pragma unroll
    for (int ni = 0; ni < 2; ++ni) {
        const int c = n0 + wn * 32 + ni * 16 + lr;
        const float bias = bo[c];
#pragma unroll
        for (int mi = 0; mi < 2; ++mi)
#pragma unroll
            for (int r = 0; r < 4; ++r) {
                const int row = m0 + wm * 32 + mi * 16 + lg * 4 + r;
                out[(size_t)row * CH + c] = acc[mi][ni][r] + bias;
            }
    }
}

// ---------------- flash attention: 4-wave additive s-split, 32x32 MFMA ----------------
// Swapped QK^T: S^T = mfma32(A=K, B=Q).  C/D: col=q=lane&31, row=s=(g&3)+8*(g>>2)+4h.
// m==0 softmax => partial (O, lsum) additive across waves; tree combine in LDS.
// K/V compacted + fragment-major => all frag loads are 1KB coalesced wave-loads.
// R22: T14 register prefetch — issue tile i+4's K/V loads before computing tile i,
// rotate at loop bottom; waitcnt sinks past QK^T+exp+PV (backend doesn't SW-pipeline).
// Prefetch index i32+4 <= 46 < 64 tiles: always in-bounds; overshoot values never used.
__global__ __launch_bounds__(256, 4) void attn_kernel(
    const u16* __restrict__ q_ws, const u16* __restrict__ k_ws,
    const u16* __restrict__ v_t, u16* __restrict__ attout) {
    const int bid = blockIdx.x;
    const int xcd = bid & 7, idx = bid >> 3;
    const int bn = xcd + 8 * (idx >> 6);      // 4 bn per XCD -> K/V/Q L2-resident
    const int qb = 63 - (idx & 63);           // longest q-blocks first
    const int q0 = qb * 32;
    const int l = threadIdx.x & 63;
    const int w = threadIdx.x >> 6;
    const int ql = l & 31, h = l >> 5;

    const int t = q0 + ql;
    const int kct = kc_of(t);                 // per-lane causal boundary (compact idx)
    const int kcq0 = kc_of(q0);               // block-uniform
    const int kcmax = kc_of(q0 + 31);         // block-uniform
    const int ntc32 = (kcmax + 31) >> 5;

    const size_t baseq = (size_t)bn * CT * CD;
    const size_t basek = (size_t)bn * CT * CD;
    const size_t basev = (size_t)bn * CD * CT;

    // Q as B-operand: lane holds Q[q0+ql][16c + 8h + j]
    bf16x8 qf[4];
    {
        const u16* qp = q_ws + baseq + (size_t)t * CD + h * 8;
#pragma unroll
        for (int c = 0; c < 4; ++c) qf[c] = *(const bf16x8*)(qp + c * 16);
    }

    f32x16 oa[2];
#pragma unroll
    for (int dh = 0; dh < 2; ++dh)
#pragma unroll
        for (int e = 0; e < 16; ++e) oa[dh][e] = 0.f;
    float lsum = 0.f;

    // per-lane fragment offsets (u16 units)
    const int koff0 = ((0 * 2 + h) * 32 + ql) * 8;
    const int kstep = 2 * 32 * 8;  // c -> c+1

    // prologue: load K/V frags for first tile (tile index w < 64: in-bounds even if unused)
    bf16x8 kf[4], vf[4];
    {
        const u16* kt0 = k_ws + basek + (size_t)w * 2048;
        const u16* vt0 = v_t + basev + (size_t)w * 2048;
#pragma unroll
        for (int c = 0; c < 4; ++c) kf[c] = *(const bf16x8*)(kt0 + koff0 + c * kstep);
#pragma unroll
        for (int u = 0; u < 4; ++u) vf[u] = *(const bf16x8*)(vt0 + koff0 + u * kstep);
    }

    for (int i32 = w; i32 < ntc32; i32 += 4) {
        const int s0h = i32 * 32;
        const bool needmask = (s0h + 31 >= kcq0);   // tail: per-element causal

        // prefetch next tile's K/V frags (overlaps the whole compute phase below)
        bf16x8 kn[4], vn[4];
        {
            const u16* kt2 = k_ws + basek + (size_t)(i32 + 4) * 2048;
            const u16* vt2 = v_t + basev + (size_t)(i32 + 4) * 2048;
#pragma unroll
            for (int c = 0; c < 4; ++c) kn[c] = *(const bf16x8*)(kt2 + koff0 + c * kstep);
#pragma unroll
            for (int u = 0; u < 4; ++u) vn[u] = *(const bf16x8*)(vt2 + koff0 + u * kstep);
        }

        // S^T = K · Q^T with current kf
        f32x16 sa;
#pragma unroll
        for (int e = 0; e < 16; ++e) sa[e] = 0.f;
#pragma unroll
        for (int c = 0; c < 4; ++c)
            sa = MFMA32(kf[c], qf[c], sa);

        // p = exp2(s'), per-lane lsum (no cross-lane ops)
        float pr[16];
        if (needmask) {
#pragma unroll
            for (int g = 0; g < 16; ++g) {
                const int roff = (g & 3) + 8 * (g >> 2);
                float e = __builtin_amdgcn_exp2f(sa[g]);
                e = (s0h + roff + 4 * h < kct) ? e : 0.f;
                lsum += e;
                pr[g] = e;
            }
        } else {
#pragma unroll
            for (int g = 0; g < 16; ++g) {
                float e = __builtin_amdgcn_exp2f(sa[g]);
                lsum += e;
                pr[g] = e;
            }
        }

        // Pack P to bf16 A-frags in-register (half-exchange via shfl_xor(32)+select)
#pragma unroll
        for (int kb = 0; kb < 2; ++kb) {
            const int g0 = kb * 8;
            unsigned int w0, w1, w2, w3;
            asm("v_cvt_pk_bf16_f32 %0, %1, %2" : "=v"(w0) : "v"(pr[g0 + 0]), "v"(pr[g0 + 1]));
            asm("v_cvt_pk_bf16_f32 %0, %1, %2" : "=v"(w1) : "v"(pr[g0 + 2]), "v"(pr[g0 + 3]));
            asm("v_cvt_pk_bf16_f32 %0, %1, %2" : "=v"(w2) : "v"(pr[g0 + 4]), "v"(pr[g0 + 5]));
            asm("v_cvt_pk_bf16_f32 %0, %1, %2" : "=v"(w3) : "v"(pr[g0 + 6]), "v"(pr[g0 + 7]));
            const unsigned int x0 = (unsigned int)__shfl_xor((int)w0, 32);
            const unsigned int x1 = (unsigned int)__shfl_xor((int)w1, 32);
            const unsigned int x2 = (unsigned int)__shfl_xor((int)w2, 32);
            const unsigned int x3 = (unsigned int)__shfl_xor((int)w3, 32);
            u32x4 fw;
            fw.x = h ? x2 : w0;
            fw.y = h ? x3 : w1;
            fw.z = h ? w2 : x0;
            fw.w = h ? w3 : x1;
            const bf16x8 pa = __builtin_bit_cast(bf16x8, fw);
#pragma unroll
            for (int dh = 0; dh < 2; ++dh)
                oa[dh] = MFMA32(pa, vf[dh * 2 + kb], oa[dh]);
        }

        // rotate prefetched frags into place
#pragma unroll
        for (int c = 0; c < 4; ++c) { kf[c] = kn[c]; vf[c] = vn[c]; }
    }

    // ---- additive tree combine across the 4 waves (2 buffers, 17.6 KB LDS) ----
    __shared__ float buf[2][64][33];
    __shared__ float lsp[4][64];
    __shared__ float lsf[32];

    lsp[w][l] = lsum;
    if (w >= 2) {
#pragma unroll
        for (int dh = 0; dh < 2; ++dh)
#pragma unroll
            for (int g = 0; g < 16; ++g)
                buf[w - 2][l][dh * 16 + g] = oa[dh][g];
    }
    __syncthreads();
    if (w < 2) {
#pragma unroll
        for (int dh = 0; dh < 2; ++dh)
#pragma unroll
            for (int g = 0; g < 16; ++g)
                oa[dh][g] += buf[w][l][dh * 16 + g];
    }
    if (threadIdx.x < 32) {
        const int r = threadIdx.x;
        float s = 0.f;
#pragma unroll
        for (int ww = 0; ww < 4; ++ww) s += lsp[ww][r] + lsp[ww][r + 32];
        lsf[r] = 1.f / s;
    }
    __syncthreads();
    if (w == 1) {
#pragma unroll
        for (int dh = 0; dh < 2; ++dh)
#pragma unroll
            for (int g = 0; g < 16; ++g)
                buf[0][l][dh * 16 + g] = oa[dh][g];
    }
    __syncthreads();
    if (w == 0) {
        const int b = bn >> 3, nh = bn & 7;
#pragma unroll
        for (int dh = 0; dh < 2; ++dh)
#pragma unroll
            for (int g = 0; g < 16; ++g) {
                const float s = oa[dh][g] + buf[0][l][dh * 16 + g];
                const int r = (g & 3) + 8 * (g >> 2) + 4 * h;
                attout[(size_t)(b * CT + q0 + r) * CH + nh * 64 + dh * 32 + ql] = f2bf(s * lsf[r]);
            }
    }
}

// ---------------- launcher ----------------

extern "C" void kernel_launch(void* const* d_in, const int* in_sizes, int n_in,
                              void* d_out, int out_size, void* d_ws, size_t ws_size,
                              hipStream_t stream) {
    const float* x  = (const float*)d_in[0];
    const float* Wq = (const float*)d_in[1];
    const float* bq = (const float*)d_in[2];
    const float* Wk = (const float*)d_in[3];
    const float* bk = (const float*)d_in[4];
    const float* Wv = (const float*)d_in[5];
    const float* bv = (const float*)d_in[6];
    const float* Wo = (const float*)d_in[7];
    const float* bo = (const float*)d_in[8];
    float* out = (float*)d_out;

    char* p = (char*)d_ws;
    u16* xb = (u16*)p;        p += (size_t)CM * CH * 2;        // 8 MB
    u16* Wt = (u16*)p;        p += (size_t)4 * CH * CH * 2;    // 2 MB
    float2* tab = (float2*)p; p += (size_t)CT * (CH / 2) * 8;  // 4 MB
    u16* q_ws = (u16*)p;      p += (size_t)CM * CH * 2;        // 8 MB
    u16* k_ws = (u16*)p;      p += (size_t)CM * CH * 2;        // 8 MB (frag-major tiles)
    u16* v_t  = (u16*)p;      p += (size_t)CM * CH * 2;        // 8 MB (frag-major tiles)
    u16* attout = (u16*)p;    p += (size_t)CM * CH * 2;        // 8 MB

    prep_kernel<<<dim3(5120), 256, 0, stream>>>(x, xb, Wq, Wk, Wv, Wo, Wt, tab);
    gemm_qkv_kernel<<<dim3(CM / 128, (3 * CH) / 128), 512, 0, stream>>>(
        xb, Wt, bq, bk, bv, tab, q_ws, k_ws, v_t);
    attn_kernel<<<dim3(2048), 256, 0, stream>>>(q_ws, k_ws, v_t, attout);
    gemm_out_kernel<<<dim3(CM / 64, CH / 128), 512, 0, stream>>>(
        attout, Wt + (size_t)3 * CH * CH, bo, out);
}